// Round 7
// baseline (3499.676 us; speedup 1.0000x reference)
//
#include <hip/hip_runtime.h>

typedef unsigned short ushort_t;
typedef _Float16 half_t;
typedef __attribute__((ext_vector_type(8))) _Float16 half8;
typedef __attribute__((ext_vector_type(4))) float f32x4;

#define B_ 256
#define T_ 200
#define X_ 128
#define H_ 512

// swizzled weight offsets in d_ws (f16 elements)
#define OFF_WO1 0
#define OFF_WO2 57344
#define OFF_WU1 122880
#define OFF_WR1 251904
#define OFF_WN1 380928
#define OFF_WU2 509952
#define OFF_WR2 575488
#define OFF_WN2 641024
#define OFF_WT1 772096
#define OFF_WT2 886784
#define OFF_WT3 901120
#define SWZ_TOTAL 1032192
#define DTS_BYTE_OFF (SWZ_TOTAL * 2)

#define LOG2E 1.4426950408889634f

// ===== r24 = r23 + S1/S3 K-split: [hs|x] partials on S1's idle waves. =====
//  Ledger:
//  r12/r14/r18/r19/r20: VGPR budget immovable at 64; deep unroll CLOSED
//       (note: r24's LDS ~86KB genuinely forces 1 block/CU -> backend may
//        now legitimately raise the budget; watch VGPR_Count).
//  r15 split-K with +2 barriers: +8.5%. CLOSED for barrier-adding variants.
//  r16 x-hoist CLOSED. r22 fp8: +150us (overhead > byte savings). CLOSED.
//  r21 (kept): S6->S0 barrier merge; x_{t+1} prefetch after S0 barrier.
//  r23 (kept, 2800us steady): pair-tile af dedup in S2/S4/S6; eliminated
//       2MB of in-loop spill traffic (WRITE_SIZE 3072->1024).
//  r24: yc@W1 = h_ode@W1[0:512] + [hs|x]@W1[512:1152]. The [hs|x] half is
//       known at S0; compute it as 28 KB-10 pieces (f32 partials in LDS,
//       stride-17 padded) on the 9 waves that idled during S1 (+1 piece on
//       each S1 wave). S3 shrinks KB36->KB16 with acc init from partials.
//       Zero new barriers. Probe: -4-9% => chain-unit cost high => S5 split
//       (+1 barrier) justified next; flat => close K-split family.
//  Tripwires: WRITE_SIZE ~1024 (no spill), absmax ~9.8e-4, LDS ~86KB.

struct Args {
  const float *x_data, *x_time;
  const float *Wu1, *bu1, *Wu2, *bu2;
  const float *Wr1, *br1, *Wr2, *br2;
  const float *Wn1, *bn1, *Wn2, *bn2;
  const float *Wo1, *bo1, *Wo2, *bo2;
  const float *Wt1, *bt1, *Wt2, *bt2, *Wt3, *bt3;
  float* out;      // f32 output: mu[256*512] then sigma[256*512]
  half_t* wsw;     // swizzled weights (f16)
  float* dts;      // 200 per-step dt values
};

// hw-instruction activations (validated r12/r13: VALU -70%, absmax unchanged)
__device__ __forceinline__ float fast_sigm(float x) {
  return __builtin_amdgcn_rcpf(1.0f + __builtin_amdgcn_exp2f(-LOG2E * x));
}
__device__ __forceinline__ float fast_tanh(float x) {
  return 1.0f - 2.0f * __builtin_amdgcn_rcpf(1.0f + __builtin_amdgcn_exp2f((2.0f * LOG2E) * x));
}

// One 16x16 output tile, K = KB*32. A from LDS, B from pre-swizzled global.
// Keep "#pragma unroll 4" (deep unroll closed at the 64-VGPR cap).
template <int KB>
__device__ __forceinline__ f32x4 gemm_tile(const half_t* __restrict__ wtile,
                                           const half_t* __restrict__ abase,
                                           int astride, int lane, f32x4 acc) {
  const half_t* ap = abase + (lane & 15) * astride + 8 * (lane >> 4);
  const half_t* wp = wtile + lane * 8;
#pragma unroll 4
  for (int kb = 0; kb < KB; ++kb) {
    half8 af = *(const half8*)(ap + kb * 32);
    half8 bf = *(const half8*)(wp + kb * 512);
    acc = __builtin_amdgcn_mfma_f32_16x16x32_f16(af, bf, acc, 0, 0, 0);
  }
  return acc;
}

// Two tiles sharing one A-fragment load (r23: the af dedup + spill-free win).
template <int KB>
__device__ __forceinline__ void gemm_tile2(const half_t* __restrict__ w0,
                                           const half_t* __restrict__ w1,
                                           const half_t* __restrict__ abase,
                                           int astride, int lane,
                                           f32x4& acc0, f32x4& acc1) {
  const half_t* ap = abase + (lane & 15) * astride + 8 * (lane >> 4);
  const half_t* wp0 = w0 + lane * 8;
  const half_t* wp1 = w1 + lane * 8;
#pragma unroll 2
  for (int kb = 0; kb < KB; ++kb) {
    half8 af = *(const half8*)(ap + kb * 32);
    half8 b0 = *(const half8*)(wp0 + kb * 512);
    half8 b1 = *(const half8*)(wp1 + kb * 512);
    acc0 = __builtin_amdgcn_mfma_f32_16x16x32_f16(af, b0, acc0, 0, 0, 0);
    acc1 = __builtin_amdgcn_mfma_f32_16x16x32_f16(af, b1, acc1, 0, 0, 0);
  }
}

// Pre-swizzle f32 weights into f16 MFMA B-fragment layout, K padded to mult of
// 32 (zeros), N padded to mult of 16 (zeros).
__global__ void swz_kernel(Args a) {
  struct WT { const float* src; int off; int KB; int Kr; int Nr; };
  const WT tbl[11] = {
      {a.Wo1, OFF_WO1, 16, 512, 100},  {a.Wo2, OFF_WO2, 4, 100, 512},
      {a.Wu1, OFF_WU1, 36, 1152, 100}, {a.Wr1, OFF_WR1, 36, 1152, 100},
      {a.Wn1, OFF_WN1, 36, 1152, 100}, {a.Wu2, OFF_WU2, 4, 100, 512},
      {a.Wr2, OFF_WR2, 4, 100, 512},   {a.Wn2, OFF_WN2, 4, 100, 1024},
      {a.Wt1, OFF_WT1, 32, 1024, 100}, {a.Wt2, OFF_WT2, 4, 100, 100},
      {a.Wt3, OFF_WT3, 4, 100, 1024}};
  const int ends[11] = {OFF_WO2, OFF_WU1, OFF_WR1, OFF_WN1, OFF_WU2, OFF_WR2,
                        OFF_WN2, OFF_WT1, OFF_WT2, OFF_WT3, SWZ_TOTAL};
  int gid = blockIdx.x * blockDim.x + threadIdx.x;
  int e8 = gid * 8;
  if (e8 >= SWZ_TOTAL) return;
  int w = 0;
  while (e8 >= ends[w]) ++w;
  const WT T = tbl[w];
  int local = e8 - T.off;
  int lane = (local >> 3) & 63;
  int blk = local >> 9;  // nt*KB + kb
  int kb = blk % T.KB, nt = blk / T.KB;
  int n = nt * 16 + (lane & 15);
  int k0 = kb * 32 + 8 * (lane >> 4);
#pragma unroll
  for (int j = 0; j < 8; ++j) {
    int k = k0 + j;
    float v = (k < T.Kr && n < T.Nr) ? T.src[k * T.Nr + n] : 0.0f;
    a.wsw[e8 + j] = (half_t)v;
  }
}

__global__ void dts_kernel(Args a) {
  int t = threadIdx.x;
  if (t >= T_) return;
  float v;
  if (t == 0)      v = -0.01f;
  else if (t == 1) v = a.x_time[T_ - 1] - a.x_time[0];
  else             v = a.x_time[t - 2] - a.x_time[t - 1];
  a.dts[t] = v;
}

// Persistent ODE-GRU scan: 16 blocks x 1024 threads; block b owns batch rows
// [16b,16b+16). State in registers at C-fragment positions:
//   hreg[s*4+i] = h[m=g*4+i][n=(wave+s*16)*16+lm]  (s=0,1)
__global__ __launch_bounds__(1024) void odegru_kernel(Args a) {
  // yc stride 1160 f16 (=580 dw == 4 mod 32 -> 2-way-free LDS banks)
  __shared__ __align__(16) half_t yc[16 * 1160];   // [h_ode | hs | x] then c
  __shared__ __align__(16) half_t tg[16 * 136];
  __shared__ __align__(16) half_t tu[16 * 136];
  __shared__ __align__(16) half_t tr[16 * 136];
  __shared__ __align__(16) half_t tn[16 * 136];
  // f32 partials for the [hs|x] half of S3's GEMMs: 28 pieces (14 tiles x 2
  // K-halves), row stride 17 (bank spread). Written in P1, read in P3.
  __shared__ __align__(16) float pur[28 * 272];
  __shared__ float dts_s[T_];

  const int tid = threadIdx.x;
  const int wave = tid >> 6;
  const int lane = tid & 63;
  const int lm = lane & 15;
  const int g = lane >> 4;
  const int row0 = blockIdx.x * 16;

  for (int i = tid; i < 16 * 136; i += 1024) {
    tg[i] = (half_t)0.f; tu[i] = (half_t)0.f; tr[i] = (half_t)0.f; tn[i] = (half_t)0.f;
  }
  if (tid < T_) dts_s[tid] = a.dts[tid];

  // x prefetch: thread covers (xm, xk) and (xm+8, xk); 2048 elems per step.
  const int xm = tid >> 7, xk = tid & 127;
  const float* xb0 = a.x_data + (long)(row0 + xm) * T_ * X_ + xk;
  const float* xb1 = xb0 + (long)8 * T_ * X_;
  float xp0 = xb0[0];  // t = 0 (exposed once, before the loop)
  float xp1 = xb1[0];

  float hreg[8], hsreg[8];
#pragma unroll
  for (int i = 0; i < 8; ++i) { hreg[i] = 0.f; hsreg[i] = 0.f; }
  float ureg[8];  // u gate: producer wave == consumer wave
  __syncthreads();

  // piece p (0..27): tile t=p>>1 (U:0-6, R:7-13), K-half h=p&1.
  // Weight kb range 16+10h..25+10h of the 36-kb tile; A cols 512+320h.
  auto do_piece = [&](int p) {
    int t2 = p >> 1, half = p & 1;
    bool isU = t2 < 7;
    int nt7 = isU ? t2 : t2 - 7;
    f32x4 acc = {0.f, 0.f, 0.f, 0.f};
    acc = gemm_tile<10>(
        a.wsw + (isU ? OFF_WU1 : OFF_WR1) + nt7 * 36 * 512 + (16 + 10 * half) * 512,
        yc + 512 + half * 320, 1160, lane, acc);
#pragma unroll
    for (int i = 0; i < 4; ++i)
      pur[p * 272 + (g * 4 + i) * 17 + lm] = acc[i];
  };

  for (int t = 0; t < T_; ++t) {
    const float dt = dts_s[t];
    // ---- S0: yc = [f16(h) | f16(hs) | f16(x_t)] (merged with S6 tail) ----
#pragma unroll
    for (int s = 0; s < 2; ++s) {
      int n = (wave + s * 16) * 16 + lm;
#pragma unroll
      for (int i = 0; i < 4; ++i) {
        int m = g * 4 + i;
        yc[m * 1160 + n]       = (half_t)hreg[s * 4 + i];
        yc[m * 1160 + 512 + n] = (half_t)hsreg[s * 4 + i];
      }
    }
    yc[xm * 1160 + 1024 + xk]       = (half_t)xp0;
    yc[(xm + 8) * 1160 + 1024 + xk] = (half_t)xp1;
    __syncthreads();
    // x_{t+1} prefetch after the barrier (r21-validated placement).
    if (t + 1 < T_) {
      xp0 = xb0[(t + 1) * X_];
      xp1 = xb1[(t + 1) * X_];
    }
    // ---- P1: track A (waves 0-6): tg = tanh(h @ Wo1 + bo1), + 1 piece each.
    //      track B (waves 7-15): 21 remaining [hs|x] partial pieces. ----
    if (wave < 7) {
      f32x4 acc = {0.f, 0.f, 0.f, 0.f};
      acc = gemm_tile<16>(a.wsw + OFF_WO1 + wave * 16 * 512, yc, 1160, lane, acc);
      int n = wave * 16 + lm;
      if (n < 100) {
        float bias = a.bo1[n];
#pragma unroll
        for (int i = 0; i < 4; ++i)
          tg[(g * 4 + i) * 136 + n] = (half_t)fast_tanh(acc[i] + bias);
      }
      do_piece(wave);  // pieces 0-6
    } else {
      int j = wave - 7;  // 0..8 -> pieces 7..27 (3,3,3,2,2,2,2,2,2)
      int p0 = j < 3 ? 7 + j * 3 : 16 + (j - 3) * 2;
      int cnt = j < 3 ? 3 : 2;
      for (int k = 0; k < cnt; ++k) do_piece(p0 + k);
    }
    __syncthreads();
    // ---- S2: h_ode = h + dt*(tg @ Wo2 + bo2); hreg := h_ode; yc := f16(h_ode)
    {
      f32x4 acc0 = {0.f, 0.f, 0.f, 0.f}, acc1 = {0.f, 0.f, 0.f, 0.f};
      gemm_tile2<4>(a.wsw + OFF_WO2 + wave * 4 * 512,
                    a.wsw + OFF_WO2 + (wave + 16) * 4 * 512,
                    tg, 136, lane, acc0, acc1);
#pragma unroll
      for (int s = 0; s < 2; ++s) {
        const f32x4& acc = s ? acc1 : acc0;
        int n = (wave + s * 16) * 16 + lm;
        float bias = a.bo2[n];
#pragma unroll
        for (int i = 0; i < 4; ++i) {
          int m = g * 4 + i;
          float h_ode = hreg[s * 4 + i] + dt * (acc[i] + bias);
          hreg[s * 4 + i] = h_ode;
          yc[m * 1160 + n] = (half_t)h_ode;
        }
      }
    }
    __syncthreads();
    // ---- P3: tu/tr = tanh(h_ode @ W1[0:512] + partials + bias) (KB16) ----
    for (int nt = wave; nt < 14; nt += 16) {
      bool isU = nt < 7;
      int nt7 = isU ? nt : nt - 7;
      f32x4 acc;
#pragma unroll
      for (int i = 0; i < 4; ++i)
        acc[i] = pur[(2 * nt) * 272 + (g * 4 + i) * 17 + lm] +
                 pur[(2 * nt + 1) * 272 + (g * 4 + i) * 17 + lm];
      acc = gemm_tile<16>(a.wsw + (isU ? OFF_WU1 : OFF_WR1) + nt7 * 36 * 512,
                          yc, 1160, lane, acc);
      int n = nt7 * 16 + lm;
      if (n < 100) {
        float bias = (isU ? a.bu1 : a.br1)[n];
        half_t* dst = isU ? tu : tr;
#pragma unroll
        for (int i = 0; i < 4; ++i)
          dst[(g * 4 + i) * 136 + n] = (half_t)fast_tanh(acc[i] + bias);
      }
    }
    __syncthreads();
    // ---- S4: u -> ureg ; r -> fused c-build into yc (pair-tile af sharing) --
    {
      f32x4 acc0 = {0.f, 0.f, 0.f, 0.f}, acc1 = {0.f, 0.f, 0.f, 0.f};
      gemm_tile2<4>(a.wsw + OFF_WU2 + wave * 4 * 512,
                    a.wsw + OFF_WU2 + (wave + 16) * 4 * 512,
                    tu, 136, lane, acc0, acc1);
#pragma unroll
      for (int s = 0; s < 2; ++s) {
        const f32x4& acc = s ? acc1 : acc0;
        int n = (wave + s * 16) * 16 + lm;
        float bias = a.bu2[n];
#pragma unroll
        for (int i = 0; i < 4; ++i) ureg[s * 4 + i] = fast_sigm(acc[i] + bias);
      }
    }
    {
      f32x4 acc0 = {0.f, 0.f, 0.f, 0.f}, acc1 = {0.f, 0.f, 0.f, 0.f};
      gemm_tile2<4>(a.wsw + OFF_WR2 + wave * 4 * 512,
                    a.wsw + OFF_WR2 + (wave + 16) * 4 * 512,
                    tr, 136, lane, acc0, acc1);
#pragma unroll
      for (int s = 0; s < 2; ++s) {
        const f32x4& acc = s ? acc1 : acc0;
        int n = (wave + s * 16) * 16 + lm;
        float bias = a.br2[n];
#pragma unroll
        for (int i = 0; i < 4; ++i) {
          int m = g * 4 + i;
          float r = fast_sigm(acc[i] + bias);
          yc[m * 1160 + n]       = (half_t)(hreg[s * 4 + i] * r);
          yc[m * 1160 + 512 + n] = (half_t)(hsreg[s * 4 + i] * r);
        }
      }
    }
    __syncthreads();
    // ---- S5: tn = tanh(c @ Wn1 + bn1) ----
    for (int nt = wave; nt < 7; nt += 16) {
      f32x4 acc = {0.f, 0.f, 0.f, 0.f};
      acc = gemm_tile<36>(a.wsw + OFF_WN1 + nt * 36 * 512, yc, 1160, lane, acc);
      int n = nt * 16 + lm;
      if (n < 100) {
        float bias = a.bn1[n];
#pragma unroll
        for (int i = 0; i < 4; ++i)
          tn[(g * 4 + i) * 136 + n] = (half_t)fast_tanh(acc[i] + bias);
      }
    }
    __syncthreads();
    // ---- S6: ns = tn @ Wn2 + bn2; gated state update (2x pair-tile) ----
    //      (no trailing barrier: merged with next step's S0)
    {
      f32x4 acc0 = {0.f, 0.f, 0.f, 0.f}, acc1 = {0.f, 0.f, 0.f, 0.f};
      gemm_tile2<4>(a.wsw + OFF_WN2 + wave * 4 * 512,
                    a.wsw + OFF_WN2 + (wave + 16) * 4 * 512,
                    tn, 136, lane, acc0, acc1);
#pragma unroll
      for (int s = 0; s < 2; ++s) {  // m-part -> h update
        const f32x4& acc = s ? acc1 : acc0;
        int n = (wave + s * 16) * 16 + lm;
        float bias = a.bn2[n];
#pragma unroll
        for (int i = 0; i < 4; ++i) {
          float u = ureg[s * 4 + i];
          float mval = acc[i] + bias;
          hreg[s * 4 + i] = (1.0f - u) * mval + u * hreg[s * 4 + i];
        }
      }
    }
    {
      f32x4 acc0 = {0.f, 0.f, 0.f, 0.f}, acc1 = {0.f, 0.f, 0.f, 0.f};
      gemm_tile2<4>(a.wsw + OFF_WN2 + (wave + 32) * 4 * 512,
                    a.wsw + OFF_WN2 + (wave + 48) * 4 * 512,
                    tn, 136, lane, acc0, acc1);
#pragma unroll
      for (int s = 0; s < 2; ++s) {  // s-part -> hs update
        const f32x4& acc = s ? acc1 : acc0;
        int n = (wave + 32 + s * 16) * 16 + lm;
        float bias = a.bn2[n];
#pragma unroll
        for (int i = 0; i < 4; ++i) {
          float u = ureg[s * 4 + i];
          float sval = fabsf(acc[i] + bias);
          hsreg[s * 4 + i] = (1.0f - u) * sval + u * hsreg[s * 4 + i];
        }
      }
    }
  }

  // ---- Final decoder ----
#pragma unroll
  for (int s = 0; s < 2; ++s) {
    int n = (wave + s * 16) * 16 + lm;
#pragma unroll
    for (int i = 0; i < 4; ++i) {
      int m = g * 4 + i;
      yc[m * 1160 + n]       = (half_t)hreg[s * 4 + i];
      yc[m * 1160 + 512 + n] = (half_t)hsreg[s * 4 + i];
    }
  }
  __syncthreads();
  for (int nt = wave; nt < 7; nt += 16) {  // z1 = tanh(hcat@Wt1+bt1)
    f32x4 acc = {0.f, 0.f, 0.f, 0.f};
    acc = gemm_tile<32>(a.wsw + OFF_WT1 + nt * 32 * 512, yc, 1160, lane, acc);
    int n = nt * 16 + lm;
    if (n < 100) {
      float bias = a.bt1[n];
#pragma unroll
      for (int i = 0; i < 4; ++i)
        tu[(g * 4 + i) * 136 + n] = (half_t)fast_tanh(acc[i] + bias);
    }
  }
  __syncthreads();
  for (int nt = wave; nt < 7; nt += 16) {  // z2 = tanh(z1@Wt2+bt2)
    f32x4 acc = {0.f, 0.f, 0.f, 0.f};
    acc = gemm_tile<4>(a.wsw + OFF_WT2 + nt * 4 * 512, tu, 136, lane, acc);
    int n = nt * 16 + lm;
    if (n < 100) {
      float bias = a.bt2[n];
#pragma unroll
      for (int i = 0; i < 4; ++i)
        tr[(g * 4 + i) * 136 + n] = (half_t)fast_tanh(acc[i] + bias);
    }
  }
  __syncthreads();
#pragma unroll
  for (int s = 0; s < 4; ++s) {  // z3 = z2@Wt3+bt3 -> mu | sigma (f32 out)
    int nt = wave + s * 16;
    f32x4 acc = {0.f, 0.f, 0.f, 0.f};
    acc = gemm_tile<4>(a.wsw + OFF_WT3 + nt * 4 * 512, tr, 136, lane, acc);
    int n = nt * 16 + lm;
    float bias = a.bt3[n];
#pragma unroll
    for (int i = 0; i < 4; ++i) {
      int grow = row0 + g * 4 + i;
      float val = acc[i] + bias;
      if (n < 512)
        a.out[(size_t)grow * 512 + n] = val;
      else
        a.out[(size_t)(B_ * 512) + (size_t)grow * 512 + (n - 512)] = fabsf(val);
    }
  }
}

extern "C" void kernel_launch(void* const* d_in, const int* in_sizes, int n_in,
                              void* d_out, int out_size, void* d_ws, size_t ws_size,
                              hipStream_t stream) {
  Args a;
  a.x_data = (const float*)d_in[0];
  a.x_time = (const float*)d_in[1];
  a.Wu1 = (const float*)d_in[2];  a.bu1 = (const float*)d_in[3];
  a.Wu2 = (const float*)d_in[4];  a.bu2 = (const float*)d_in[5];
  a.Wr1 = (const float*)d_in[6];  a.br1 = (const float*)d_in[7];
  a.Wr2 = (const float*)d_in[8];  a.br2 = (const float*)d_in[9];
  a.Wn1 = (const float*)d_in[10]; a.bn1 = (const float*)d_in[11];
  a.Wn2 = (const float*)d_in[12]; a.bn2 = (const float*)d_in[13];
  a.Wo1 = (const float*)d_in[14]; a.bo1 = (const float*)d_in[15];
  a.Wo2 = (const float*)d_in[16]; a.bo2 = (const float*)d_in[17];
  a.Wt1 = (const float*)d_in[18]; a.bt1 = (const float*)d_in[19];
  a.Wt2 = (const float*)d_in[20]; a.bt2 = (const float*)d_in[21];
  a.Wt3 = (const float*)d_in[22]; a.bt3 = (const float*)d_in[23];
  a.out = (float*)d_out;
  a.wsw = (half_t*)d_ws;
  a.dts = (float*)((char*)d_ws + DTS_BYTE_OFF);

  swz_kernel<<<dim3(504), dim3(256), 0, stream>>>(a);
  dts_kernel<<<dim3(1), dim3(256), 0, stream>>>(a);
  odegru_kernel<<<dim3(16), dim3(1024), 0, stream>>>(a);
}

// Round 8
// 3021.199 us; speedup vs baseline: 1.1584x; 1.1584x over previous
//
#include <hip/hip_runtime.h>

typedef unsigned short ushort_t;
typedef _Float16 half_t;
typedef __attribute__((ext_vector_type(8))) _Float16 half8;
typedef __attribute__((ext_vector_type(4))) float f32x4;

#define B_ 256
#define T_ 200
#define X_ 128
#define H_ 512

// swizzled weight offsets in d_ws (f16 elements)
#define OFF_WO1 0
#define OFF_WO2 57344
#define OFF_WU1 122880
#define OFF_WR1 251904
#define OFF_WN1 380928
#define OFF_WU2 509952
#define OFF_WR2 575488
#define OFF_WN2 641024
#define OFF_WT1 772096
#define OFF_WT2 886784
#define OFF_WT3 901120
#define SWZ_TOTAL 1032192
#define DTS_BYTE_OFF (SWZ_TOTAL * 2)

#define LOG2E 1.4426950408889634f

// ===== r25 = r23 + dual-K-chain in S1/S3/S5 (zero-cost ILP). Ledger: =====
//  r12/r14/r18/r19/r20: VGPR budget immovable at 64; deep unroll CLOSED.
//  r15 split-K (+2 barriers): +8.5%. CLOSED.
//  r16 x-hoist via HBM epilogue: +5%. CLOSED.
//  r22 fp8 S1/S2: +150us (cvt overhead > byte savings; latency-bound, not
//       byte-bound). CLOSED.
//  r24 K-split via LDS partials: +600us (spills returned WRITE 1024->2432,
//       +2.2M conflicts, P1 became the long pole at 30 units). LDS-partial
//       rebalancing family CLOSED — 2nd failure of this shape after r15/r16.
//  r21 (kept): S6->S0 barrier merge (6 barriers/step); x_{t+1} prefetch
//       AFTER the S0 barrier (before it, vmcnt(0) drain killed overlap).
//  r23 (kept, 2800us steady): pair-tile af dedup in S2/S4/S6; killed 2MB of
//       in-loop spill traffic (WRITE_SIZE 3072->1024).
//  r25: phases are latency-stall bound (no pipe >45% on active CUs). Each
//       S3/S5 tile = 36 serial kb-units (9 unroll-4 groups x ~250cy L2).
//       Dual-K-chain: same wave, two independent half-K streams with two
//       accumulators, interleaved, acc0+acc1 at end. Serial latency ~halves.
//       Register-neutral: 2 streams x unroll 2 = 4 loads in flight = same 32
//       VGPRs as unroll 4; extra acc lives in AGPR.
//  Tripwires: WRITE_SIZE ~1024 (>2MB => spill, revert to r23), LDS 55808,
//       VGPR 64, absmax ~9.8e-4. Flat result => TLP already hides latency;
//       close ILP line (structural floor).

struct Args {
  const float *x_data, *x_time;
  const float *Wu1, *bu1, *Wu2, *bu2;
  const float *Wr1, *br1, *Wr2, *br2;
  const float *Wn1, *bn1, *Wn2, *bn2;
  const float *Wo1, *bo1, *Wo2, *bo2;
  const float *Wt1, *bt1, *Wt2, *bt2, *Wt3, *bt3;
  float* out;      // f32 output: mu[256*512] then sigma[256*512]
  half_t* wsw;     // swizzled weights (f16)
  float* dts;      // 200 per-step dt values
};

// hw-instruction activations (validated r12/r13: VALU -70%, absmax unchanged)
__device__ __forceinline__ float fast_sigm(float x) {
  return __builtin_amdgcn_rcpf(1.0f + __builtin_amdgcn_exp2f(-LOG2E * x));
}
__device__ __forceinline__ float fast_tanh(float x) {
  return 1.0f - 2.0f * __builtin_amdgcn_rcpf(1.0f + __builtin_amdgcn_exp2f((2.0f * LOG2E) * x));
}

// One 16x16 output tile, K = KB*32. A from LDS, B from pre-swizzled global.
// Keep "#pragma unroll 4" (deep unroll closed at the 64-VGPR cap).
template <int KB>
__device__ __forceinline__ f32x4 gemm_tile(const half_t* __restrict__ wtile,
                                           const half_t* __restrict__ abase,
                                           int astride, int lane, f32x4 acc) {
  const half_t* ap = abase + (lane & 15) * astride + 8 * (lane >> 4);
  const half_t* wp = wtile + lane * 8;
#pragma unroll 4
  for (int kb = 0; kb < KB; ++kb) {
    half8 af = *(const half8*)(ap + kb * 32);
    half8 bf = *(const half8*)(wp + kb * 512);
    acc = __builtin_amdgcn_mfma_f32_16x16x32_f16(af, bf, acc, 0, 0, 0);
  }
  return acc;
}

// Dual-K-chain tile: split K into two independent half-chains in the SAME
// wave (two accumulators, interleaved issue, summed at the end). Halves the
// serial load-latency chain without extra registers: 2 streams x unroll 2 =
// 4 loads in flight = identical to gemm_tile's unroll 4.
template <int KB>
__device__ __forceinline__ f32x4 gemm_tile_dual(const half_t* __restrict__ wtile,
                                                const half_t* __restrict__ abase,
                                                int astride, int lane) {
  constexpr int H = KB / 2;
  const half_t* ap = abase + (lane & 15) * astride + 8 * (lane >> 4);
  const half_t* wp = wtile + lane * 8;
  f32x4 a0 = {0.f, 0.f, 0.f, 0.f};
  f32x4 a1 = {0.f, 0.f, 0.f, 0.f};
#pragma unroll 2
  for (int kb = 0; kb < H; ++kb) {
    half8 af0 = *(const half8*)(ap + kb * 32);
    half8 bf0 = *(const half8*)(wp + kb * 512);
    half8 af1 = *(const half8*)(ap + (kb + H) * 32);
    half8 bf1 = *(const half8*)(wp + (kb + H) * 512);
    a0 = __builtin_amdgcn_mfma_f32_16x16x32_f16(af0, bf0, a0, 0, 0, 0);
    a1 = __builtin_amdgcn_mfma_f32_16x16x32_f16(af1, bf1, a1, 0, 0, 0);
  }
  return a0 + a1;
}

// Two tiles sharing one A-fragment load (r23: the af dedup + spill-free win).
template <int KB>
__device__ __forceinline__ void gemm_tile2(const half_t* __restrict__ w0,
                                           const half_t* __restrict__ w1,
                                           const half_t* __restrict__ abase,
                                           int astride, int lane,
                                           f32x4& acc0, f32x4& acc1) {
  const half_t* ap = abase + (lane & 15) * astride + 8 * (lane >> 4);
  const half_t* wp0 = w0 + lane * 8;
  const half_t* wp1 = w1 + lane * 8;
#pragma unroll 2
  for (int kb = 0; kb < KB; ++kb) {
    half8 af = *(const half8*)(ap + kb * 32);
    half8 b0 = *(const half8*)(wp0 + kb * 512);
    half8 b1 = *(const half8*)(wp1 + kb * 512);
    acc0 = __builtin_amdgcn_mfma_f32_16x16x32_f16(af, b0, acc0, 0, 0, 0);
    acc1 = __builtin_amdgcn_mfma_f32_16x16x32_f16(af, b1, acc1, 0, 0, 0);
  }
}

// Pre-swizzle f32 weights into f16 MFMA B-fragment layout, K padded to mult of
// 32 (zeros), N padded to mult of 16 (zeros).
__global__ void swz_kernel(Args a) {
  struct WT { const float* src; int off; int KB; int Kr; int Nr; };
  const WT tbl[11] = {
      {a.Wo1, OFF_WO1, 16, 512, 100},  {a.Wo2, OFF_WO2, 4, 100, 512},
      {a.Wu1, OFF_WU1, 36, 1152, 100}, {a.Wr1, OFF_WR1, 36, 1152, 100},
      {a.Wn1, OFF_WN1, 36, 1152, 100}, {a.Wu2, OFF_WU2, 4, 100, 512},
      {a.Wr2, OFF_WR2, 4, 100, 512},   {a.Wn2, OFF_WN2, 4, 100, 1024},
      {a.Wt1, OFF_WT1, 32, 1024, 100}, {a.Wt2, OFF_WT2, 4, 100, 100},
      {a.Wt3, OFF_WT3, 4, 100, 1024}};
  const int ends[11] = {OFF_WO2, OFF_WU1, OFF_WR1, OFF_WN1, OFF_WU2, OFF_WR2,
                        OFF_WN2, OFF_WT1, OFF_WT2, OFF_WT3, SWZ_TOTAL};
  int gid = blockIdx.x * blockDim.x + threadIdx.x;
  int e8 = gid * 8;
  if (e8 >= SWZ_TOTAL) return;
  int w = 0;
  while (e8 >= ends[w]) ++w;
  const WT T = tbl[w];
  int local = e8 - T.off;
  int lane = (local >> 3) & 63;
  int blk = local >> 9;  // nt*KB + kb
  int kb = blk % T.KB, nt = blk / T.KB;
  int n = nt * 16 + (lane & 15);
  int k0 = kb * 32 + 8 * (lane >> 4);
#pragma unroll
  for (int j = 0; j < 8; ++j) {
    int k = k0 + j;
    float v = (k < T.Kr && n < T.Nr) ? T.src[k * T.Nr + n] : 0.0f;
    a.wsw[e8 + j] = (half_t)v;
  }
}

__global__ void dts_kernel(Args a) {
  int t = threadIdx.x;
  if (t >= T_) return;
  float v;
  if (t == 0)      v = -0.01f;
  else if (t == 1) v = a.x_time[T_ - 1] - a.x_time[0];
  else             v = a.x_time[t - 2] - a.x_time[t - 1];
  a.dts[t] = v;
}

// Persistent ODE-GRU scan: 16 blocks x 1024 threads; block b owns batch rows
// [16b,16b+16). State in registers at C-fragment positions:
//   hreg[s*4+i] = h[m=g*4+i][n=(wave+s*16)*16+lm]  (s=0,1)
__global__ __launch_bounds__(1024) void odegru_kernel(Args a) {
  // yc stride 1160 f16 (=580 dw == 4 mod 32 -> 2-way-free LDS banks)
  __shared__ __align__(16) half_t yc[16 * 1160];   // [h_ode | hs | x] then c
  __shared__ __align__(16) half_t tg[16 * 136];
  __shared__ __align__(16) half_t tu[16 * 136];
  __shared__ __align__(16) half_t tr[16 * 136];
  __shared__ __align__(16) half_t tn[16 * 136];
  __shared__ float dts_s[T_];

  const int tid = threadIdx.x;
  const int wave = tid >> 6;
  const int lane = tid & 63;
  const int lm = lane & 15;
  const int g = lane >> 4;
  const int row0 = blockIdx.x * 16;

  for (int i = tid; i < 16 * 136; i += 1024) {
    tg[i] = (half_t)0.f; tu[i] = (half_t)0.f; tr[i] = (half_t)0.f; tn[i] = (half_t)0.f;
  }
  if (tid < T_) dts_s[tid] = a.dts[tid];

  // x prefetch: thread covers (xm, xk) and (xm+8, xk); 2048 elems per step.
  const int xm = tid >> 7, xk = tid & 127;
  const float* xb0 = a.x_data + (long)(row0 + xm) * T_ * X_ + xk;
  const float* xb1 = xb0 + (long)8 * T_ * X_;
  float xp0 = xb0[0];  // t = 0 (exposed once, before the loop)
  float xp1 = xb1[0];

  float hreg[8], hsreg[8];
#pragma unroll
  for (int i = 0; i < 8; ++i) { hreg[i] = 0.f; hsreg[i] = 0.f; }
  float ureg[8];  // u gate: producer wave == consumer wave
  __syncthreads();

  for (int t = 0; t < T_; ++t) {
    const float dt = dts_s[t];
    // ---- S0: yc = [f16(h) | f16(hs) | f16(x_t)] (merged with S6 tail:
    //          no barrier between S6 and S0 — S6 reads tn/regs, S0 writes yc;
    //          S5's yc reads are fenced by the S5->S6 barrier)
#pragma unroll
    for (int s = 0; s < 2; ++s) {
      int n = (wave + s * 16) * 16 + lm;
#pragma unroll
      for (int i = 0; i < 4; ++i) {
        int m = g * 4 + i;
        yc[m * 1160 + n]       = (half_t)hreg[s * 4 + i];
        yc[m * 1160 + 512 + n] = (half_t)hsreg[s * 4 + i];
      }
    }
    yc[xm * 1160 + 1024 + xk]       = (half_t)xp0;
    yc[(xm + 8) * 1160 + 1024 + xk] = (half_t)xp1;
    __syncthreads();
    // x_{t+1} prefetch issued AFTER the barrier: drains at the end-of-S1
    // barrier, i.e. the HBM miss hides under S1's MFMA work.
    if (t + 1 < T_) {
      xp0 = xb0[(t + 1) * X_];
      xp1 = xb1[(t + 1) * X_];
    }
    // ---- S1: tg = tanh(h @ Wo1 + bo1) (dual-K: 2x8 chains) ----
    for (int nt = wave; nt < 7; nt += 16) {
      f32x4 acc = gemm_tile_dual<16>(a.wsw + OFF_WO1 + nt * 16 * 512, yc, 1160, lane);
      int n = nt * 16 + lm;
      if (n < 100) {
        float bias = a.bo1[n];
#pragma unroll
        for (int i = 0; i < 4; ++i)
          tg[(g * 4 + i) * 136 + n] = (half_t)fast_tanh(acc[i] + bias);
      }
    }
    __syncthreads();
    // ---- S2: h_ode = h + dt*(tg @ Wo2 + bo2); hreg := h_ode; yc := f16(h_ode)
    //      (pair-tile: one af read feeds both s=0/s=1 accumulators) ----
    {
      f32x4 acc0 = {0.f, 0.f, 0.f, 0.f}, acc1 = {0.f, 0.f, 0.f, 0.f};
      gemm_tile2<4>(a.wsw + OFF_WO2 + wave * 4 * 512,
                    a.wsw + OFF_WO2 + (wave + 16) * 4 * 512,
                    tg, 136, lane, acc0, acc1);
#pragma unroll
      for (int s = 0; s < 2; ++s) {
        const f32x4& acc = s ? acc1 : acc0;
        int n = (wave + s * 16) * 16 + lm;
        float bias = a.bo2[n];
#pragma unroll
        for (int i = 0; i < 4; ++i) {
          int m = g * 4 + i;
          float h_ode = hreg[s * 4 + i] + dt * (acc[i] + bias);
          hreg[s * 4 + i] = h_ode;
          yc[m * 1160 + n] = (half_t)h_ode;
        }
      }
    }
    __syncthreads();
    // ---- S3: tu = tanh(yc@Wu1+bu1), tr = tanh(yc@Wr1+br1) (14 tiles,
    //      dual-K: 2x18 chains) ----
    for (int nt = wave; nt < 14; nt += 16) {
      bool isU = nt < 7;
      int nt7 = isU ? nt : nt - 7;
      f32x4 acc = gemm_tile_dual<36>(
          a.wsw + (isU ? OFF_WU1 : OFF_WR1) + nt7 * 36 * 512, yc, 1160, lane);
      int n = nt7 * 16 + lm;
      if (n < 100) {
        float bias = (isU ? a.bu1 : a.br1)[n];
        half_t* dst = isU ? tu : tr;
#pragma unroll
        for (int i = 0; i < 4; ++i)
          dst[(g * 4 + i) * 136 + n] = (half_t)fast_tanh(acc[i] + bias);
      }
    }
    __syncthreads();
    // ---- S4: u -> ureg ; r -> fused c-build into yc (pair-tile af sharing) --
    {
      f32x4 acc0 = {0.f, 0.f, 0.f, 0.f}, acc1 = {0.f, 0.f, 0.f, 0.f};
      gemm_tile2<4>(a.wsw + OFF_WU2 + wave * 4 * 512,
                    a.wsw + OFF_WU2 + (wave + 16) * 4 * 512,
                    tu, 136, lane, acc0, acc1);
#pragma unroll
      for (int s = 0; s < 2; ++s) {
        const f32x4& acc = s ? acc1 : acc0;
        int n = (wave + s * 16) * 16 + lm;
        float bias = a.bu2[n];
#pragma unroll
        for (int i = 0; i < 4; ++i) ureg[s * 4 + i] = fast_sigm(acc[i] + bias);
      }
    }
    {
      f32x4 acc0 = {0.f, 0.f, 0.f, 0.f}, acc1 = {0.f, 0.f, 0.f, 0.f};
      gemm_tile2<4>(a.wsw + OFF_WR2 + wave * 4 * 512,
                    a.wsw + OFF_WR2 + (wave + 16) * 4 * 512,
                    tr, 136, lane, acc0, acc1);
#pragma unroll
      for (int s = 0; s < 2; ++s) {
        const f32x4& acc = s ? acc1 : acc0;
        int n = (wave + s * 16) * 16 + lm;
        float bias = a.br2[n];
#pragma unroll
        for (int i = 0; i < 4; ++i) {
          int m = g * 4 + i;
          float r = fast_sigm(acc[i] + bias);
          yc[m * 1160 + n]       = (half_t)(hreg[s * 4 + i] * r);
          yc[m * 1160 + 512 + n] = (half_t)(hsreg[s * 4 + i] * r);
        }
      }
    }
    __syncthreads();
    // ---- S5: tn = tanh(c @ Wn1 + bn1) (dual-K: 2x18 chains) ----
    for (int nt = wave; nt < 7; nt += 16) {
      f32x4 acc = gemm_tile_dual<36>(a.wsw + OFF_WN1 + nt * 36 * 512, yc, 1160, lane);
      int n = nt * 16 + lm;
      if (n < 100) {
        float bias = a.bn1[n];
#pragma unroll
        for (int i = 0; i < 4; ++i)
          tn[(g * 4 + i) * 136 + n] = (half_t)fast_tanh(acc[i] + bias);
      }
    }
    __syncthreads();
    // ---- S6: ns = tn @ Wn2 + bn2; gated state update (2x pair-tile) ----
    //      (no trailing barrier: merged with next step's S0)
    {
      f32x4 acc0 = {0.f, 0.f, 0.f, 0.f}, acc1 = {0.f, 0.f, 0.f, 0.f};
      gemm_tile2<4>(a.wsw + OFF_WN2 + wave * 4 * 512,
                    a.wsw + OFF_WN2 + (wave + 16) * 4 * 512,
                    tn, 136, lane, acc0, acc1);
#pragma unroll
      for (int s = 0; s < 2; ++s) {  // m-part -> h update
        const f32x4& acc = s ? acc1 : acc0;
        int n = (wave + s * 16) * 16 + lm;
        float bias = a.bn2[n];
#pragma unroll
        for (int i = 0; i < 4; ++i) {
          float u = ureg[s * 4 + i];
          float mval = acc[i] + bias;
          hreg[s * 4 + i] = (1.0f - u) * mval + u * hreg[s * 4 + i];
        }
      }
    }
    {
      f32x4 acc0 = {0.f, 0.f, 0.f, 0.f}, acc1 = {0.f, 0.f, 0.f, 0.f};
      gemm_tile2<4>(a.wsw + OFF_WN2 + (wave + 32) * 4 * 512,
                    a.wsw + OFF_WN2 + (wave + 48) * 4 * 512,
                    tn, 136, lane, acc0, acc1);
#pragma unroll
      for (int s = 0; s < 2; ++s) {  // s-part -> hs update
        const f32x4& acc = s ? acc1 : acc0;
        int n = (wave + 32 + s * 16) * 16 + lm;
        float bias = a.bn2[n];
#pragma unroll
        for (int i = 0; i < 4; ++i) {
          float u = ureg[s * 4 + i];
          float sval = fabsf(acc[i] + bias);
          hsreg[s * 4 + i] = (1.0f - u) * sval + u * hsreg[s * 4 + i];
        }
      }
    }
  }

  // ---- Final decoder ----
#pragma unroll
  for (int s = 0; s < 2; ++s) {
    int n = (wave + s * 16) * 16 + lm;
#pragma unroll
    for (int i = 0; i < 4; ++i) {
      int m = g * 4 + i;
      yc[m * 1160 + n]       = (half_t)hreg[s * 4 + i];
      yc[m * 1160 + 512 + n] = (half_t)hsreg[s * 4 + i];
    }
  }
  __syncthreads();
  for (int nt = wave; nt < 7; nt += 16) {  // z1 = tanh(hcat@Wt1+bt1)
    f32x4 acc = {0.f, 0.f, 0.f, 0.f};
    acc = gemm_tile<32>(a.wsw + OFF_WT1 + nt * 32 * 512, yc, 1160, lane, acc);
    int n = nt * 16 + lm;
    if (n < 100) {
      float bias = a.bt1[n];
#pragma unroll
      for (int i = 0; i < 4; ++i)
        tu[(g * 4 + i) * 136 + n] = (half_t)fast_tanh(acc[i] + bias);
    }
  }
  __syncthreads();
  for (int nt = wave; nt < 7; nt += 16) {  // z2 = tanh(z1@Wt2+bt2)
    f32x4 acc = {0.f, 0.f, 0.f, 0.f};
    acc = gemm_tile<4>(a.wsw + OFF_WT2 + nt * 4 * 512, tu, 136, lane, acc);
    int n = nt * 16 + lm;
    if (n < 100) {
      float bias = a.bt2[n];
#pragma unroll
      for (int i = 0; i < 4; ++i)
        tr[(g * 4 + i) * 136 + n] = (half_t)fast_tanh(acc[i] + bias);
    }
  }
  __syncthreads();
#pragma unroll
  for (int s = 0; s < 4; ++s) {  // z3 = z2@Wt3+bt3 -> mu | sigma (f32 out)
    int nt = wave + s * 16;
    f32x4 acc = {0.f, 0.f, 0.f, 0.f};
    acc = gemm_tile<4>(a.wsw + OFF_WT3 + nt * 4 * 512, tr, 136, lane, acc);
    int n = nt * 16 + lm;
    float bias = a.bt3[n];
#pragma unroll
    for (int i = 0; i < 4; ++i) {
      int grow = row0 + g * 4 + i;
      float val = acc[i] + bias;
      if (n < 512)
        a.out[(size_t)grow * 512 + n] = val;
      else
        a.out[(size_t)(B_ * 512) + (size_t)grow * 512 + (n - 512)] = fabsf(val);
    }
  }
}

extern "C" void kernel_launch(void* const* d_in, const int* in_sizes, int n_in,
                              void* d_out, int out_size, void* d_ws, size_t ws_size,
                              hipStream_t stream) {
  Args a;
  a.x_data = (const float*)d_in[0];
  a.x_time = (const float*)d_in[1];
  a.Wu1 = (const float*)d_in[2];  a.bu1 = (const float*)d_in[3];
  a.Wu2 = (const float*)d_in[4];  a.bu2 = (const float*)d_in[5];
  a.Wr1 = (const float*)d_in[6];  a.br1 = (const float*)d_in[7];
  a.Wr2 = (const float*)d_in[8];  a.br2 = (const float*)d_in[9];
  a.Wn1 = (const float*)d_in[10]; a.bn1 = (const float*)d_in[11];
  a.Wn2 = (const float*)d_in[12]; a.bn2 = (const float*)d_in[13];
  a.Wo1 = (const float*)d_in[14]; a.bo1 = (const float*)d_in[15];
  a.Wo2 = (const float*)d_in[16]; a.bo2 = (const float*)d_in[17];
  a.Wt1 = (const float*)d_in[18]; a.bt1 = (const float*)d_in[19];
  a.Wt2 = (const float*)d_in[20]; a.bt2 = (const float*)d_in[21];
  a.Wt3 = (const float*)d_in[22]; a.bt3 = (const float*)d_in[23];
  a.out = (float*)d_out;
  a.wsw = (half_t*)d_ws;
  a.dts = (float*)((char*)d_ws + DTS_BYTE_OFF);

  swz_kernel<<<dim3(504), dim3(256), 0, stream>>>(a);
  dts_kernel<<<dim3(1), dim3(256), 0, stream>>>(a);
  odegru_kernel<<<dim3(16), dim3(1024), 0, stream>>>(a);
}

// Round 9
// 2981.835 us; speedup vs baseline: 1.1737x; 1.0132x over previous
//
#include <hip/hip_runtime.h>

typedef unsigned short ushort_t;
typedef _Float16 half_t;
typedef __attribute__((ext_vector_type(8))) _Float16 half8;
typedef __attribute__((ext_vector_type(4))) float f32x4;

#define B_ 256
#define T_ 200
#define X_ 128
#define H_ 512

// swizzled weight offsets in d_ws (f16 elements)
#define OFF_WO1 0
#define OFF_WO2 57344
#define OFF_WU1 122880
#define OFF_WR1 251904
#define OFF_WN1 380928
#define OFF_WU2 509952
#define OFF_WR2 575488
#define OFF_WN2 641024
#define OFF_WT1 772096
#define OFF_WT2 886784
#define OFF_WT3 901120
#define SWZ_TOTAL 1032192
#define DTS_BYTE_OFF (SWZ_TOTAL * 2)

#define LOG2E 1.4426950408889634f

// In-loop barrier: LDS-only ordering (ds_write retire -> s_barrier). Unlike
// __syncthreads it does NOT drain vmcnt, so the x_{t+1} register prefetch
// issued before the S0 barrier stays in flight across the whole step.
// Correct because the loop's producer->consumer traffic is exclusively LDS
// (no in-loop global writes); producer drains its own lgkmcnt pre-barrier.
#define SYNC() asm volatile("s_waitcnt lgkmcnt(0)\ns_barrier" ::: "memory")

// ===== r26 = r23 + lgkm-only barriers + u-gate moved S4->S6. Ledger: =====
//  r12/r14/r18/r19/r20: VGPR budget immovable at 64; deep unroll CLOSED.
//  r15 split-K (+2 barriers): +8.5%. CLOSED.
//  r16 x-hoist via HBM epilogue: +5%. CLOSED.
//  r22 fp8 S1/S2: +150us (cvt VALU > byte savings; latency- not byte-bound).
//       CLOSED.
//  r24 K-split via LDS partials: +600us (spills + conflicts + P1 long pole).
//       LDS-partial rebalancing CLOSED.
//  r25 dual-K-chain: 2800->2926. Two unroll-2 streams halved per-stream
//       prefetch depth; 4-wave TLP already covered the latency. ILP CLOSED.
//  r21 (kept): S6->S0 barrier merge (6 barriers/step).
//  r23 (kept, 2800us steady): pair-tile af dedup in S2/S4/S6; killed 2MB of
//       in-loop spill traffic (WRITE_SIZE 3072->1024).
//  r26a: in-loop __syncthreads -> SYNC() (lgkm-only). Removes 6 vmcnt(0)
//       drains/step; x-prefetch now floats across all 6 phases.
//  r26b: u = sigm(tu@Wu2+bu2) moved from S4 into S6 (tu untouched after S3;
//       u consumed by same wave in S6). S4 chain 8->4 units; S6 gains an
//       independent 4-unit chain (issue-overlapped); ureg live range now
//       within-S6 (-8 VGPR pressure across S5). Bit-identical numerics.
//  Tripwires: absmax must be EXACTLY 0.0009765625 (else barrier bug ->
//       revert); WRITE_SIZE ~1024; VGPR 64; LDS 55808. Flat dur => phase
//       structure at floor; declare ceiling with best kernel.

struct Args {
  const float *x_data, *x_time;
  const float *Wu1, *bu1, *Wu2, *bu2;
  const float *Wr1, *br1, *Wr2, *br2;
  const float *Wn1, *bn1, *Wn2, *bn2;
  const float *Wo1, *bo1, *Wo2, *bo2;
  const float *Wt1, *bt1, *Wt2, *bt2, *Wt3, *bt3;
  float* out;      // f32 output: mu[256*512] then sigma[256*512]
  half_t* wsw;     // swizzled weights (f16)
  float* dts;      // 200 per-step dt values
};

// hw-instruction activations (validated r12/r13: VALU -70%, absmax unchanged)
__device__ __forceinline__ float fast_sigm(float x) {
  return __builtin_amdgcn_rcpf(1.0f + __builtin_amdgcn_exp2f(-LOG2E * x));
}
__device__ __forceinline__ float fast_tanh(float x) {
  return 1.0f - 2.0f * __builtin_amdgcn_rcpf(1.0f + __builtin_amdgcn_exp2f((2.0f * LOG2E) * x));
}

// One 16x16 output tile, K = KB*32. A from LDS, B from pre-swizzled global.
// Keep "#pragma unroll 4" (deep unroll AND dual-chain variants both closed).
template <int KB>
__device__ __forceinline__ f32x4 gemm_tile(const half_t* __restrict__ wtile,
                                           const half_t* __restrict__ abase,
                                           int astride, int lane, f32x4 acc) {
  const half_t* ap = abase + (lane & 15) * astride + 8 * (lane >> 4);
  const half_t* wp = wtile + lane * 8;
#pragma unroll 4
  for (int kb = 0; kb < KB; ++kb) {
    half8 af = *(const half8*)(ap + kb * 32);
    half8 bf = *(const half8*)(wp + kb * 512);
    acc = __builtin_amdgcn_mfma_f32_16x16x32_f16(af, bf, acc, 0, 0, 0);
  }
  return acc;
}

// Two tiles sharing one A-fragment load (r23: the af dedup + spill-free win).
template <int KB>
__device__ __forceinline__ void gemm_tile2(const half_t* __restrict__ w0,
                                           const half_t* __restrict__ w1,
                                           const half_t* __restrict__ abase,
                                           int astride, int lane,
                                           f32x4& acc0, f32x4& acc1) {
  const half_t* ap = abase + (lane & 15) * astride + 8 * (lane >> 4);
  const half_t* wp0 = w0 + lane * 8;
  const half_t* wp1 = w1 + lane * 8;
#pragma unroll 2
  for (int kb = 0; kb < KB; ++kb) {
    half8 af = *(const half8*)(ap + kb * 32);
    half8 b0 = *(const half8*)(wp0 + kb * 512);
    half8 b1 = *(const half8*)(wp1 + kb * 512);
    acc0 = __builtin_amdgcn_mfma_f32_16x16x32_f16(af, b0, acc0, 0, 0, 0);
    acc1 = __builtin_amdgcn_mfma_f32_16x16x32_f16(af, b1, acc1, 0, 0, 0);
  }
}

// Pre-swizzle f32 weights into f16 MFMA B-fragment layout, K padded to mult of
// 32 (zeros), N padded to mult of 16 (zeros).
__global__ void swz_kernel(Args a) {
  struct WT { const float* src; int off; int KB; int Kr; int Nr; };
  const WT tbl[11] = {
      {a.Wo1, OFF_WO1, 16, 512, 100},  {a.Wo2, OFF_WO2, 4, 100, 512},
      {a.Wu1, OFF_WU1, 36, 1152, 100}, {a.Wr1, OFF_WR1, 36, 1152, 100},
      {a.Wn1, OFF_WN1, 36, 1152, 100}, {a.Wu2, OFF_WU2, 4, 100, 512},
      {a.Wr2, OFF_WR2, 4, 100, 512},   {a.Wn2, OFF_WN2, 4, 100, 1024},
      {a.Wt1, OFF_WT1, 32, 1024, 100}, {a.Wt2, OFF_WT2, 4, 100, 100},
      {a.Wt3, OFF_WT3, 4, 100, 1024}};
  const int ends[11] = {OFF_WO2, OFF_WU1, OFF_WR1, OFF_WN1, OFF_WU2, OFF_WR2,
                        OFF_WN2, OFF_WT1, OFF_WT2, OFF_WT3, SWZ_TOTAL};
  int gid = blockIdx.x * blockDim.x + threadIdx.x;
  int e8 = gid * 8;
  if (e8 >= SWZ_TOTAL) return;
  int w = 0;
  while (e8 >= ends[w]) ++w;
  const WT T = tbl[w];
  int local = e8 - T.off;
  int lane = (local >> 3) & 63;
  int blk = local >> 9;  // nt*KB + kb
  int kb = blk % T.KB, nt = blk / T.KB;
  int n = nt * 16 + (lane & 15);
  int k0 = kb * 32 + 8 * (lane >> 4);
#pragma unroll
  for (int j = 0; j < 8; ++j) {
    int k = k0 + j;
    float v = (k < T.Kr && n < T.Nr) ? T.src[k * T.Nr + n] : 0.0f;
    a.wsw[e8 + j] = (half_t)v;
  }
}

__global__ void dts_kernel(Args a) {
  int t = threadIdx.x;
  if (t >= T_) return;
  float v;
  if (t == 0)      v = -0.01f;
  else if (t == 1) v = a.x_time[T_ - 1] - a.x_time[0];
  else             v = a.x_time[t - 2] - a.x_time[t - 1];
  a.dts[t] = v;
}

// Persistent ODE-GRU scan: 16 blocks x 1024 threads; block b owns batch rows
// [16b,16b+16). State in registers at C-fragment positions:
//   hreg[s*4+i] = h[m=g*4+i][n=(wave+s*16)*16+lm]  (s=0,1)
__global__ __launch_bounds__(1024) void odegru_kernel(Args a) {
  // yc stride 1160 f16 (=580 dw == 4 mod 32 -> 2-way-free LDS banks)
  __shared__ __align__(16) half_t yc[16 * 1160];   // [h_ode | hs | x] then c
  __shared__ __align__(16) half_t tg[16 * 136];
  __shared__ __align__(16) half_t tu[16 * 136];
  __shared__ __align__(16) half_t tr[16 * 136];
  __shared__ __align__(16) half_t tn[16 * 136];
  __shared__ float dts_s[T_];

  const int tid = threadIdx.x;
  const int wave = tid >> 6;
  const int lane = tid & 63;
  const int lm = lane & 15;
  const int g = lane >> 4;
  const int row0 = blockIdx.x * 16;

  for (int i = tid; i < 16 * 136; i += 1024) {
    tg[i] = (half_t)0.f; tu[i] = (half_t)0.f; tr[i] = (half_t)0.f; tn[i] = (half_t)0.f;
  }
  if (tid < T_) dts_s[tid] = a.dts[tid];

  // x prefetch: thread covers (xm, xk) and (xm+8, xk); 2048 elems per step.
  const int xm = tid >> 7, xk = tid & 127;
  const float* xb0 = a.x_data + (long)(row0 + xm) * T_ * X_ + xk;
  const float* xb1 = xb0 + (long)8 * T_ * X_;
  float xp0 = xb0[0];  // t = 0 (exposed once, before the loop)
  float xp1 = xb1[0];

  float hreg[8], hsreg[8];
#pragma unroll
  for (int i = 0; i < 8; ++i) { hreg[i] = 0.f; hsreg[i] = 0.f; }
  __syncthreads();

  for (int t = 0; t < T_; ++t) {
    const float dt = dts_s[t];
    // ---- S0: yc = [f16(h) | f16(hs) | f16(x_t)] (merged with S6 tail:
    //          no barrier between S6 and S0 — S6 reads tn/tu/regs, S0 writes
    //          yc; S5's yc reads are fenced by the S5->S6 barrier)
#pragma unroll
    for (int s = 0; s < 2; ++s) {
      int n = (wave + s * 16) * 16 + lm;
#pragma unroll
      for (int i = 0; i < 4; ++i) {
        int m = g * 4 + i;
        yc[m * 1160 + n]       = (half_t)hreg[s * 4 + i];
        yc[m * 1160 + 512 + n] = (half_t)hsreg[s * 4 + i];
      }
    }
    yc[xm * 1160 + 1024 + xk]       = (half_t)xp0;
    yc[(xm + 8) * 1160 + 1024 + xk] = (half_t)xp1;
    // x_{t+1} prefetch issued BEFORE the barrier: SYNC() is lgkm-only, so
    // these loads float across all 6 phases and drain only at next step's
    // S0 store. (With __syncthreads this was impossible — vmcnt(0) drain.)
    if (t + 1 < T_) {
      xp0 = xb0[(t + 1) * X_];
      xp1 = xb1[(t + 1) * X_];
    }
    SYNC();
    // ---- S1: tg = tanh(h @ Wo1 + bo1) ----
    for (int nt = wave; nt < 7; nt += 16) {
      f32x4 acc = {0.f, 0.f, 0.f, 0.f};
      acc = gemm_tile<16>(a.wsw + OFF_WO1 + nt * 16 * 512, yc, 1160, lane, acc);
      int n = nt * 16 + lm;
      if (n < 100) {
        float bias = a.bo1[n];
#pragma unroll
        for (int i = 0; i < 4; ++i)
          tg[(g * 4 + i) * 136 + n] = (half_t)fast_tanh(acc[i] + bias);
      }
    }
    SYNC();
    // ---- S2: h_ode = h + dt*(tg @ Wo2 + bo2); hreg := h_ode; yc := f16(h_ode)
    //      (pair-tile: one af read feeds both s=0/s=1 accumulators) ----
    {
      f32x4 acc0 = {0.f, 0.f, 0.f, 0.f}, acc1 = {0.f, 0.f, 0.f, 0.f};
      gemm_tile2<4>(a.wsw + OFF_WO2 + wave * 4 * 512,
                    a.wsw + OFF_WO2 + (wave + 16) * 4 * 512,
                    tg, 136, lane, acc0, acc1);
#pragma unroll
      for (int s = 0; s < 2; ++s) {
        const f32x4& acc = s ? acc1 : acc0;
        int n = (wave + s * 16) * 16 + lm;
        float bias = a.bo2[n];
#pragma unroll
        for (int i = 0; i < 4; ++i) {
          int m = g * 4 + i;
          float h_ode = hreg[s * 4 + i] + dt * (acc[i] + bias);
          hreg[s * 4 + i] = h_ode;
          yc[m * 1160 + n] = (half_t)h_ode;
        }
      }
    }
    SYNC();
    // ---- S3: tu = tanh(yc@Wu1+bu1), tr = tanh(yc@Wr1+br1) (14 tiles) ----
    for (int nt = wave; nt < 14; nt += 16) {
      bool isU = nt < 7;
      int nt7 = isU ? nt : nt - 7;
      f32x4 acc = {0.f, 0.f, 0.f, 0.f};
      acc = gemm_tile<36>(a.wsw + (isU ? OFF_WU1 : OFF_WR1) + nt7 * 36 * 512, yc, 1160, lane, acc);
      int n = nt7 * 16 + lm;
      if (n < 100) {
        float bias = (isU ? a.bu1 : a.br1)[n];
        half_t* dst = isU ? tu : tr;
#pragma unroll
        for (int i = 0; i < 4; ++i)
          dst[(g * 4 + i) * 136 + n] = (half_t)fast_tanh(acc[i] + bias);
      }
    }
    SYNC();
    // ---- S4: r -> fused c-build into yc (u moved to S6, r26b) ----
    {
      f32x4 acc0 = {0.f, 0.f, 0.f, 0.f}, acc1 = {0.f, 0.f, 0.f, 0.f};
      gemm_tile2<4>(a.wsw + OFF_WR2 + wave * 4 * 512,
                    a.wsw + OFF_WR2 + (wave + 16) * 4 * 512,
                    tr, 136, lane, acc0, acc1);
#pragma unroll
      for (int s = 0; s < 2; ++s) {
        const f32x4& acc = s ? acc1 : acc0;
        int n = (wave + s * 16) * 16 + lm;
        float bias = a.br2[n];
#pragma unroll
        for (int i = 0; i < 4; ++i) {
          int m = g * 4 + i;
          float r = fast_sigm(acc[i] + bias);
          yc[m * 1160 + n]       = (half_t)(hreg[s * 4 + i] * r);
          yc[m * 1160 + 512 + n] = (half_t)(hsreg[s * 4 + i] * r);
        }
      }
    }
    SYNC();
    // ---- S5: tn = tanh(c @ Wn1 + bn1) ----
    for (int nt = wave; nt < 7; nt += 16) {
      f32x4 acc = {0.f, 0.f, 0.f, 0.f};
      acc = gemm_tile<36>(a.wsw + OFF_WN1 + nt * 36 * 512, yc, 1160, lane, acc);
      int n = nt * 16 + lm;
      if (n < 100) {
        float bias = a.bn1[n];
#pragma unroll
        for (int i = 0; i < 4; ++i)
          tn[(g * 4 + i) * 136 + n] = (half_t)fast_tanh(acc[i] + bias);
      }
    }
    SYNC();
    // ---- S6: u = sigm(tu@Wu2+bu2) [moved here — tu untouched since S3,
    //      consumed by this same wave]; ns = tn @ Wn2 + bn2; gated update.
    //      Three independent pair-GEMMs issue-overlap; no trailing barrier
    //      (merged with next step's S0). ----
    {
      float ureg[8];
      {
        f32x4 acc0 = {0.f, 0.f, 0.f, 0.f}, acc1 = {0.f, 0.f, 0.f, 0.f};
        gemm_tile2<4>(a.wsw + OFF_WU2 + wave * 4 * 512,
                      a.wsw + OFF_WU2 + (wave + 16) * 4 * 512,
                      tu, 136, lane, acc0, acc1);
#pragma unroll
        for (int s = 0; s < 2; ++s) {
          const f32x4& acc = s ? acc1 : acc0;
          int n = (wave + s * 16) * 16 + lm;
          float bias = a.bu2[n];
#pragma unroll
          for (int i = 0; i < 4; ++i) ureg[s * 4 + i] = fast_sigm(acc[i] + bias);
        }
      }
      {
        f32x4 acc0 = {0.f, 0.f, 0.f, 0.f}, acc1 = {0.f, 0.f, 0.f, 0.f};
        gemm_tile2<4>(a.wsw + OFF_WN2 + wave * 4 * 512,
                      a.wsw + OFF_WN2 + (wave + 16) * 4 * 512,
                      tn, 136, lane, acc0, acc1);
#pragma unroll
        for (int s = 0; s < 2; ++s) {  // m-part -> h update
          const f32x4& acc = s ? acc1 : acc0;
          int n = (wave + s * 16) * 16 + lm;
          float bias = a.bn2[n];
#pragma unroll
          for (int i = 0; i < 4; ++i) {
            float u = ureg[s * 4 + i];
            float mval = acc[i] + bias;
            hreg[s * 4 + i] = (1.0f - u) * mval + u * hreg[s * 4 + i];
          }
        }
      }
      {
        f32x4 acc0 = {0.f, 0.f, 0.f, 0.f}, acc1 = {0.f, 0.f, 0.f, 0.f};
        gemm_tile2<4>(a.wsw + OFF_WN2 + (wave + 32) * 4 * 512,
                      a.wsw + OFF_WN2 + (wave + 48) * 4 * 512,
                      tn, 136, lane, acc0, acc1);
#pragma unroll
        for (int s = 0; s < 2; ++s) {  // s-part -> hs update
          const f32x4& acc = s ? acc1 : acc0;
          int n = (wave + 32 + s * 16) * 16 + lm;
          float bias = a.bn2[n];
#pragma unroll
          for (int i = 0; i < 4; ++i) {
            float u = ureg[s * 4 + i];
            float sval = fabsf(acc[i] + bias);
            hsreg[s * 4 + i] = (1.0f - u) * sval + u * hsreg[s * 4 + i];
          }
        }
      }
    }
  }

  // ---- Final decoder ----
#pragma unroll
  for (int s = 0; s < 2; ++s) {
    int n = (wave + s * 16) * 16 + lm;
#pragma unroll
    for (int i = 0; i < 4; ++i) {
      int m = g * 4 + i;
      yc[m * 1160 + n]       = (half_t)hreg[s * 4 + i];
      yc[m * 1160 + 512 + n] = (half_t)hsreg[s * 4 + i];
    }
  }
  __syncthreads();
  for (int nt = wave; nt < 7; nt += 16) {  // z1 = tanh(hcat@Wt1+bt1)
    f32x4 acc = {0.f, 0.f, 0.f, 0.f};
    acc = gemm_tile<32>(a.wsw + OFF_WT1 + nt * 32 * 512, yc, 1160, lane, acc);
    int n = nt * 16 + lm;
    if (n < 100) {
      float bias = a.bt1[n];
#pragma unroll
      for (int i = 0; i < 4; ++i)
        tu[(g * 4 + i) * 136 + n] = (half_t)fast_tanh(acc[i] + bias);
    }
  }
  __syncthreads();
  for (int nt = wave; nt < 7; nt += 16) {  // z2 = tanh(z1@Wt2+bt2)
    f32x4 acc = {0.f, 0.f, 0.f, 0.f};
    acc = gemm_tile<4>(a.wsw + OFF_WT2 + nt * 4 * 512, tu, 136, lane, acc);
    int n = nt * 16 + lm;
    if (n < 100) {
      float bias = a.bt2[n];
#pragma unroll
      for (int i = 0; i < 4; ++i)
        tr[(g * 4 + i) * 136 + n] = (half_t)fast_tanh(acc[i] + bias);
    }
  }
  __syncthreads();
#pragma unroll
  for (int s = 0; s < 4; ++s) {  // z3 = z2@Wt3+bt3 -> mu | sigma (f32 out)
    int nt = wave + s * 16;
    f32x4 acc = {0.f, 0.f, 0.f, 0.f};
    acc = gemm_tile<4>(a.wsw + OFF_WT3 + nt * 4 * 512, tr, 136, lane, acc);
    int n = nt * 16 + lm;
    float bias = a.bt3[n];
#pragma unroll
    for (int i = 0; i < 4; ++i) {
      int grow = row0 + g * 4 + i;
      float val = acc[i] + bias;
      if (n < 512)
        a.out[(size_t)grow * 512 + n] = val;
      else
        a.out[(size_t)(B_ * 512) + (size_t)grow * 512 + (n - 512)] = fabsf(val);
    }
  }
}

extern "C" void kernel_launch(void* const* d_in, const int* in_sizes, int n_in,
                              void* d_out, int out_size, void* d_ws, size_t ws_size,
                              hipStream_t stream) {
  Args a;
  a.x_data = (const float*)d_in[0];
  a.x_time = (const float*)d_in[1];
  a.Wu1 = (const float*)d_in[2];  a.bu1 = (const float*)d_in[3];
  a.Wu2 = (const float*)d_in[4];  a.bu2 = (const float*)d_in[5];
  a.Wr1 = (const float*)d_in[6];  a.br1 = (const float*)d_in[7];
  a.Wr2 = (const float*)d_in[8];  a.br2 = (const float*)d_in[9];
  a.Wn1 = (const float*)d_in[10]; a.bn1 = (const float*)d_in[11];
  a.Wn2 = (const float*)d_in[12]; a.bn2 = (const float*)d_in[13];
  a.Wo1 = (const float*)d_in[14]; a.bo1 = (const float*)d_in[15];
  a.Wo2 = (const float*)d_in[16]; a.bo2 = (const float*)d_in[17];
  a.Wt1 = (const float*)d_in[18]; a.bt1 = (const float*)d_in[19];
  a.Wt2 = (const float*)d_in[20]; a.bt2 = (const float*)d_in[21];
  a.Wt3 = (const float*)d_in[22]; a.bt3 = (const float*)d_in[23];
  a.out = (float*)d_out;
  a.wsw = (half_t*)d_ws;
  a.dts = (float*)((char*)d_ws + DTS_BYTE_OFF);

  swz_kernel<<<dim3(504), dim3(256), 0, stream>>>(a);
  dts_kernel<<<dim3(1), dim3(256), 0, stream>>>(a);
  odegru_kernel<<<dim3(16), dim3(1024), 0, stream>>>(a);
}

// Round 10
// 2874.850 us; speedup vs baseline: 1.2173x; 1.0372x over previous
//
#include <hip/hip_runtime.h>

typedef unsigned short ushort_t;
typedef _Float16 half_t;
typedef __attribute__((ext_vector_type(8))) _Float16 half8;
typedef __attribute__((ext_vector_type(4))) float f32x4;

#define B_ 256
#define T_ 200
#define X_ 128
#define H_ 512

// swizzled weight offsets in d_ws (f16 elements)
#define OFF_WO1 0
#define OFF_WO2 57344
#define OFF_WU1 122880
#define OFF_WR1 251904
#define OFF_WN1 380928
#define OFF_WU2 509952
#define OFF_WR2 575488
#define OFF_WN2 641024
#define OFF_WT1 772096
#define OFF_WT2 886784
#define OFF_WT3 901120
#define SWZ_TOTAL 1032192
#define DTS_BYTE_OFF (SWZ_TOTAL * 2)

#define LOG2E 1.4426950408889634f

// ===== r27 = r23 VERBATIM (best verified: 2800us steady / 2874 total). =====
//  Final ledger:
//  r12/r14/r18/r19/r20: VGPR budget immovable at 64 on this ROCm (launch
//       bounds min-waves, amdgpu_waves_per_eu, LDS-pad all failed to move
//       it). Deep unroll / A-caching CLOSED.
//  r15 split-K (+2 barriers): +8.5%. r24 K-split via LDS partials: +600us
//       (spills + conflicts + new long pole). Phase-rebalancing CLOSED.
//  r16 x-hoist via HBM epilogue: +5%. CLOSED.
//  r21 (kept): S6->S0 barrier merge (6 barriers/step); x_{t+1} prefetch
//       AFTER the S0 barrier (before it, __syncthreads' vmcnt(0) drain
//       killed the overlap). -2%.
//  r22 fp8 S1/S2: +150us. cvt VALU landed 1:1 on the critical path despite
//       halving those phases' L2 bytes -> latency/issue-bound, not
//       byte-bound. fp8 CLOSED.
//  r23 (THIS KERNEL): pair-tile af dedup in S2/S4/S6 (one LDS A-fragment
//       read feeds two B n-tiles). Killed 2MB/step of in-loop scratch
//       spill traffic (WRITE_SIZE 3072->1024) + ~300 ds_read_b128/step.
//       3504 -> 2800us steady (-20%).
//  r25 dual-K-chain ILP: +125us (halved per-stream prefetch depth; 4-wave
//       TLP already covers L2 latency). ILP CLOSED.
//  r26 lgkm-only asm barriers + u-gate to S6: +110us (asm "memory" fence
//       blocks the compiler's cross-phase global-load hoisting that
//       __syncthreads permits; phase rebalance lengthened S6). CLOSED.
//  Remaining structure: 200 serial steps x 6 barrier phases, length set by
//       L2-latency-exposed weight streaming at the 64-VGPR cap. All tested
//       remedies cost more than they save. This is the structural floor of
//       this design on this compiler.

struct Args {
  const float *x_data, *x_time;
  const float *Wu1, *bu1, *Wu2, *bu2;
  const float *Wr1, *br1, *Wr2, *br2;
  const float *Wn1, *bn1, *Wn2, *bn2;
  const float *Wo1, *bo1, *Wo2, *bo2;
  const float *Wt1, *bt1, *Wt2, *bt2, *Wt3, *bt3;
  float* out;      // f32 output: mu[256*512] then sigma[256*512]
  half_t* wsw;     // swizzled weights (f16)
  float* dts;      // 200 per-step dt values
};

// hw-instruction activations (validated r12/r13: VALU -70%, absmax unchanged)
__device__ __forceinline__ float fast_sigm(float x) {
  return __builtin_amdgcn_rcpf(1.0f + __builtin_amdgcn_exp2f(-LOG2E * x));
}
__device__ __forceinline__ float fast_tanh(float x) {
  return 1.0f - 2.0f * __builtin_amdgcn_rcpf(1.0f + __builtin_amdgcn_exp2f((2.0f * LOG2E) * x));
}

// One 16x16 output tile, K = KB*32. A from LDS, B from pre-swizzled global.
// Keep "#pragma unroll 4" (deep unroll and dual-chain variants both closed).
template <int KB>
__device__ __forceinline__ f32x4 gemm_tile(const half_t* __restrict__ wtile,
                                           const half_t* __restrict__ abase,
                                           int astride, int lane, f32x4 acc) {
  const half_t* ap = abase + (lane & 15) * astride + 8 * (lane >> 4);
  const half_t* wp = wtile + lane * 8;
#pragma unroll 4
  for (int kb = 0; kb < KB; ++kb) {
    half8 af = *(const half8*)(ap + kb * 32);
    half8 bf = *(const half8*)(wp + kb * 512);
    acc = __builtin_amdgcn_mfma_f32_16x16x32_f16(af, bf, acc, 0, 0, 0);
  }
  return acc;
}

// Two tiles sharing one A-fragment load (r23: the af dedup + spill-free win).
template <int KB>
__device__ __forceinline__ void gemm_tile2(const half_t* __restrict__ w0,
                                           const half_t* __restrict__ w1,
                                           const half_t* __restrict__ abase,
                                           int astride, int lane,
                                           f32x4& acc0, f32x4& acc1) {
  const half_t* ap = abase + (lane & 15) * astride + 8 * (lane >> 4);
  const half_t* wp0 = w0 + lane * 8;
  const half_t* wp1 = w1 + lane * 8;
#pragma unroll 2
  for (int kb = 0; kb < KB; ++kb) {
    half8 af = *(const half8*)(ap + kb * 32);
    half8 b0 = *(const half8*)(wp0 + kb * 512);
    half8 b1 = *(const half8*)(wp1 + kb * 512);
    acc0 = __builtin_amdgcn_mfma_f32_16x16x32_f16(af, b0, acc0, 0, 0, 0);
    acc1 = __builtin_amdgcn_mfma_f32_16x16x32_f16(af, b1, acc1, 0, 0, 0);
  }
}

// Pre-swizzle f32 weights into f16 MFMA B-fragment layout, K padded to mult of
// 32 (zeros), N padded to mult of 16 (zeros).
__global__ void swz_kernel(Args a) {
  struct WT { const float* src; int off; int KB; int Kr; int Nr; };
  const WT tbl[11] = {
      {a.Wo1, OFF_WO1, 16, 512, 100},  {a.Wo2, OFF_WO2, 4, 100, 512},
      {a.Wu1, OFF_WU1, 36, 1152, 100}, {a.Wr1, OFF_WR1, 36, 1152, 100},
      {a.Wn1, OFF_WN1, 36, 1152, 100}, {a.Wu2, OFF_WU2, 4, 100, 512},
      {a.Wr2, OFF_WR2, 4, 100, 512},   {a.Wn2, OFF_WN2, 4, 100, 1024},
      {a.Wt1, OFF_WT1, 32, 1024, 100}, {a.Wt2, OFF_WT2, 4, 100, 100},
      {a.Wt3, OFF_WT3, 4, 100, 1024}};
  const int ends[11] = {OFF_WO2, OFF_WU1, OFF_WR1, OFF_WN1, OFF_WU2, OFF_WR2,
                        OFF_WN2, OFF_WT1, OFF_WT2, OFF_WT3, SWZ_TOTAL};
  int gid = blockIdx.x * blockDim.x + threadIdx.x;
  int e8 = gid * 8;
  if (e8 >= SWZ_TOTAL) return;
  int w = 0;
  while (e8 >= ends[w]) ++w;
  const WT T = tbl[w];
  int local = e8 - T.off;
  int lane = (local >> 3) & 63;
  int blk = local >> 9;  // nt*KB + kb
  int kb = blk % T.KB, nt = blk / T.KB;
  int n = nt * 16 + (lane & 15);
  int k0 = kb * 32 + 8 * (lane >> 4);
#pragma unroll
  for (int j = 0; j < 8; ++j) {
    int k = k0 + j;
    float v = (k < T.Kr && n < T.Nr) ? T.src[k * T.Nr + n] : 0.0f;
    a.wsw[e8 + j] = (half_t)v;
  }
}

__global__ void dts_kernel(Args a) {
  int t = threadIdx.x;
  if (t >= T_) return;
  float v;
  if (t == 0)      v = -0.01f;
  else if (t == 1) v = a.x_time[T_ - 1] - a.x_time[0];
  else             v = a.x_time[t - 2] - a.x_time[t - 1];
  a.dts[t] = v;
}

// Persistent ODE-GRU scan: 16 blocks x 1024 threads; block b owns batch rows
// [16b,16b+16). State in registers at C-fragment positions:
//   hreg[s*4+i] = h[m=g*4+i][n=(wave+s*16)*16+lm]  (s=0,1)
__global__ __launch_bounds__(1024) void odegru_kernel(Args a) {
  // yc stride 1160 f16 (=580 dw == 4 mod 32 -> 2-way-free LDS banks)
  __shared__ __align__(16) half_t yc[16 * 1160];   // [h_ode | hs | x] then c
  __shared__ __align__(16) half_t tg[16 * 136];
  __shared__ __align__(16) half_t tu[16 * 136];
  __shared__ __align__(16) half_t tr[16 * 136];
  __shared__ __align__(16) half_t tn[16 * 136];
  __shared__ float dts_s[T_];

  const int tid = threadIdx.x;
  const int wave = tid >> 6;
  const int lane = tid & 63;
  const int lm = lane & 15;
  const int g = lane >> 4;
  const int row0 = blockIdx.x * 16;

  for (int i = tid; i < 16 * 136; i += 1024) {
    tg[i] = (half_t)0.f; tu[i] = (half_t)0.f; tr[i] = (half_t)0.f; tn[i] = (half_t)0.f;
  }
  if (tid < T_) dts_s[tid] = a.dts[tid];

  // x prefetch: thread covers (xm, xk) and (xm+8, xk); 2048 elems per step.
  const int xm = tid >> 7, xk = tid & 127;
  const float* xb0 = a.x_data + (long)(row0 + xm) * T_ * X_ + xk;
  const float* xb1 = xb0 + (long)8 * T_ * X_;
  float xp0 = xb0[0];  // t = 0 (exposed once, before the loop)
  float xp1 = xb1[0];

  float hreg[8], hsreg[8];
#pragma unroll
  for (int i = 0; i < 8; ++i) { hreg[i] = 0.f; hsreg[i] = 0.f; }
  float ureg[8];  // u gate: producer wave == consumer wave
  __syncthreads();

  for (int t = 0; t < T_; ++t) {
    const float dt = dts_s[t];
    // ---- S0: yc = [f16(h) | f16(hs) | f16(x_t)] (merged with S6 tail:
    //          no barrier between S6 and S0 — S6 reads tn/regs, S0 writes yc;
    //          S5's yc reads are fenced by the S5->S6 barrier)
#pragma unroll
    for (int s = 0; s < 2; ++s) {
      int n = (wave + s * 16) * 16 + lm;
#pragma unroll
      for (int i = 0; i < 4; ++i) {
        int m = g * 4 + i;
        yc[m * 1160 + n]       = (half_t)hreg[s * 4 + i];
        yc[m * 1160 + 512 + n] = (half_t)hsreg[s * 4 + i];
      }
    }
    yc[xm * 1160 + 1024 + xk]       = (half_t)xp0;
    yc[(xm + 8) * 1160 + 1024 + xk] = (half_t)xp1;
    __syncthreads();
    // x_{t+1} prefetch issued AFTER the barrier: drains at the end-of-S1
    // barrier, i.e. the HBM miss hides under S1's MFMA work.
    if (t + 1 < T_) {
      xp0 = xb0[(t + 1) * X_];
      xp1 = xb1[(t + 1) * X_];
    }
    // ---- S1: tg = tanh(h @ Wo1 + bo1) ----
    for (int nt = wave; nt < 7; nt += 16) {
      f32x4 acc = {0.f, 0.f, 0.f, 0.f};
      acc = gemm_tile<16>(a.wsw + OFF_WO1 + nt * 16 * 512, yc, 1160, lane, acc);
      int n = nt * 16 + lm;
      if (n < 100) {
        float bias = a.bo1[n];
#pragma unroll
        for (int i = 0; i < 4; ++i)
          tg[(g * 4 + i) * 136 + n] = (half_t)fast_tanh(acc[i] + bias);
      }
    }
    __syncthreads();
    // ---- S2: h_ode = h + dt*(tg @ Wo2 + bo2); hreg := h_ode; yc := f16(h_ode)
    //      (pair-tile: one af read feeds both s=0/s=1 accumulators) ----
    {
      f32x4 acc0 = {0.f, 0.f, 0.f, 0.f}, acc1 = {0.f, 0.f, 0.f, 0.f};
      gemm_tile2<4>(a.wsw + OFF_WO2 + wave * 4 * 512,
                    a.wsw + OFF_WO2 + (wave + 16) * 4 * 512,
                    tg, 136, lane, acc0, acc1);
#pragma unroll
      for (int s = 0; s < 2; ++s) {
        const f32x4& acc = s ? acc1 : acc0;
        int n = (wave + s * 16) * 16 + lm;
        float bias = a.bo2[n];
#pragma unroll
        for (int i = 0; i < 4; ++i) {
          int m = g * 4 + i;
          float h_ode = hreg[s * 4 + i] + dt * (acc[i] + bias);
          hreg[s * 4 + i] = h_ode;
          yc[m * 1160 + n] = (half_t)h_ode;
        }
      }
    }
    __syncthreads();
    // ---- S3: tu = tanh(yc@Wu1+bu1), tr = tanh(yc@Wr1+br1) (14 tiles) ----
    for (int nt = wave; nt < 14; nt += 16) {
      bool isU = nt < 7;
      int nt7 = isU ? nt : nt - 7;
      f32x4 acc = {0.f, 0.f, 0.f, 0.f};
      acc = gemm_tile<36>(a.wsw + (isU ? OFF_WU1 : OFF_WR1) + nt7 * 36 * 512, yc, 1160, lane, acc);
      int n = nt7 * 16 + lm;
      if (n < 100) {
        float bias = (isU ? a.bu1 : a.br1)[n];
        half_t* dst = isU ? tu : tr;
#pragma unroll
        for (int i = 0; i < 4; ++i)
          dst[(g * 4 + i) * 136 + n] = (half_t)fast_tanh(acc[i] + bias);
      }
    }
    __syncthreads();
    // ---- S4: u -> ureg ; r -> fused c-build into yc (pair-tile af sharing) --
    {
      f32x4 acc0 = {0.f, 0.f, 0.f, 0.f}, acc1 = {0.f, 0.f, 0.f, 0.f};
      gemm_tile2<4>(a.wsw + OFF_WU2 + wave * 4 * 512,
                    a.wsw + OFF_WU2 + (wave + 16) * 4 * 512,
                    tu, 136, lane, acc0, acc1);
#pragma unroll
      for (int s = 0; s < 2; ++s) {
        const f32x4& acc = s ? acc1 : acc0;
        int n = (wave + s * 16) * 16 + lm;
        float bias = a.bu2[n];
#pragma unroll
        for (int i = 0; i < 4; ++i) ureg[s * 4 + i] = fast_sigm(acc[i] + bias);
      }
    }
    {
      f32x4 acc0 = {0.f, 0.f, 0.f, 0.f}, acc1 = {0.f, 0.f, 0.f, 0.f};
      gemm_tile2<4>(a.wsw + OFF_WR2 + wave * 4 * 512,
                    a.wsw + OFF_WR2 + (wave + 16) * 4 * 512,
                    tr, 136, lane, acc0, acc1);
#pragma unroll
      for (int s = 0; s < 2; ++s) {
        const f32x4& acc = s ? acc1 : acc0;
        int n = (wave + s * 16) * 16 + lm;
        float bias = a.br2[n];
#pragma unroll
        for (int i = 0; i < 4; ++i) {
          int m = g * 4 + i;
          float r = fast_sigm(acc[i] + bias);
          yc[m * 1160 + n]       = (half_t)(hreg[s * 4 + i] * r);
          yc[m * 1160 + 512 + n] = (half_t)(hsreg[s * 4 + i] * r);
        }
      }
    }
    __syncthreads();
    // ---- S5: tn = tanh(c @ Wn1 + bn1) ----
    for (int nt = wave; nt < 7; nt += 16) {
      f32x4 acc = {0.f, 0.f, 0.f, 0.f};
      acc = gemm_tile<36>(a.wsw + OFF_WN1 + nt * 36 * 512, yc, 1160, lane, acc);
      int n = nt * 16 + lm;
      if (n < 100) {
        float bias = a.bn1[n];
#pragma unroll
        for (int i = 0; i < 4; ++i)
          tn[(g * 4 + i) * 136 + n] = (half_t)fast_tanh(acc[i] + bias);
      }
    }
    __syncthreads();
    // ---- S6: ns = tn @ Wn2 + bn2; gated state update (2x pair-tile) ----
    //      (no trailing barrier: merged with next step's S0)
    {
      f32x4 acc0 = {0.f, 0.f, 0.f, 0.f}, acc1 = {0.f, 0.f, 0.f, 0.f};
      gemm_tile2<4>(a.wsw + OFF_WN2 + wave * 4 * 512,
                    a.wsw + OFF_WN2 + (wave + 16) * 4 * 512,
                    tn, 136, lane, acc0, acc1);
#pragma unroll
      for (int s = 0; s < 2; ++s) {  // m-part -> h update
        const f32x4& acc = s ? acc1 : acc0;
        int n = (wave + s * 16) * 16 + lm;
        float bias = a.bn2[n];
#pragma unroll
        for (int i = 0; i < 4; ++i) {
          float u = ureg[s * 4 + i];
          float mval = acc[i] + bias;
          hreg[s * 4 + i] = (1.0f - u) * mval + u * hreg[s * 4 + i];
        }
      }
    }
    {
      f32x4 acc0 = {0.f, 0.f, 0.f, 0.f}, acc1 = {0.f, 0.f, 0.f, 0.f};
      gemm_tile2<4>(a.wsw + OFF_WN2 + (wave + 32) * 4 * 512,
                    a.wsw + OFF_WN2 + (wave + 48) * 4 * 512,
                    tn, 136, lane, acc0, acc1);
#pragma unroll
      for (int s = 0; s < 2; ++s) {  // s-part -> hs update
        const f32x4& acc = s ? acc1 : acc0;
        int n = (wave + 32 + s * 16) * 16 + lm;
        float bias = a.bn2[n];
#pragma unroll
        for (int i = 0; i < 4; ++i) {
          float u = ureg[s * 4 + i];
          float sval = fabsf(acc[i] + bias);
          hsreg[s * 4 + i] = (1.0f - u) * sval + u * hsreg[s * 4 + i];
        }
      }
    }
  }

  // ---- Final decoder ----
#pragma unroll
  for (int s = 0; s < 2; ++s) {
    int n = (wave + s * 16) * 16 + lm;
#pragma unroll
    for (int i = 0; i < 4; ++i) {
      int m = g * 4 + i;
      yc[m * 1160 + n]       = (half_t)hreg[s * 4 + i];
      yc[m * 1160 + 512 + n] = (half_t)hsreg[s * 4 + i];
    }
  }
  __syncthreads();
  for (int nt = wave; nt < 7; nt += 16) {  // z1 = tanh(hcat@Wt1+bt1)
    f32x4 acc = {0.f, 0.f, 0.f, 0.f};
    acc = gemm_tile<32>(a.wsw + OFF_WT1 + nt * 32 * 512, yc, 1160, lane, acc);
    int n = nt * 16 + lm;
    if (n < 100) {
      float bias = a.bt1[n];
#pragma unroll
      for (int i = 0; i < 4; ++i)
        tu[(g * 4 + i) * 136 + n] = (half_t)fast_tanh(acc[i] + bias);
    }
  }
  __syncthreads();
  for (int nt = wave; nt < 7; nt += 16) {  // z2 = tanh(z1@Wt2+bt2)
    f32x4 acc = {0.f, 0.f, 0.f, 0.f};
    acc = gemm_tile<4>(a.wsw + OFF_WT2 + nt * 4 * 512, tu, 136, lane, acc);
    int n = nt * 16 + lm;
    if (n < 100) {
      float bias = a.bt2[n];
#pragma unroll
      for (int i = 0; i < 4; ++i)
        tr[(g * 4 + i) * 136 + n] = (half_t)fast_tanh(acc[i] + bias);
    }
  }
  __syncthreads();
#pragma unroll
  for (int s = 0; s < 4; ++s) {  // z3 = z2@Wt3+bt3 -> mu | sigma (f32 out)
    int nt = wave + s * 16;
    f32x4 acc = {0.f, 0.f, 0.f, 0.f};
    acc = gemm_tile<4>(a.wsw + OFF_WT3 + nt * 4 * 512, tr, 136, lane, acc);
    int n = nt * 16 + lm;
    float bias = a.bt3[n];
#pragma unroll
    for (int i = 0; i < 4; ++i) {
      int grow = row0 + g * 4 + i;
      float val = acc[i] + bias;
      if (n < 512)
        a.out[(size_t)grow * 512 + n] = val;
      else
        a.out[(size_t)(B_ * 512) + (size_t)grow * 512 + (n - 512)] = fabsf(val);
    }
  }
}

extern "C" void kernel_launch(void* const* d_in, const int* in_sizes, int n_in,
                              void* d_out, int out_size, void* d_ws, size_t ws_size,
                              hipStream_t stream) {
  Args a;
  a.x_data = (const float*)d_in[0];
  a.x_time = (const float*)d_in[1];
  a.Wu1 = (const float*)d_in[2];  a.bu1 = (const float*)d_in[3];
  a.Wu2 = (const float*)d_in[4];  a.bu2 = (const float*)d_in[5];
  a.Wr1 = (const float*)d_in[6];  a.br1 = (const float*)d_in[7];
  a.Wr2 = (const float*)d_in[8];  a.br2 = (const float*)d_in[9];
  a.Wn1 = (const float*)d_in[10]; a.bn1 = (const float*)d_in[11];
  a.Wn2 = (const float*)d_in[12]; a.bn2 = (const float*)d_in[13];
  a.Wo1 = (const float*)d_in[14]; a.bo1 = (const float*)d_in[15];
  a.Wo2 = (const float*)d_in[16]; a.bo2 = (const float*)d_in[17];
  a.Wt1 = (const float*)d_in[18]; a.bt1 = (const float*)d_in[19];
  a.Wt2 = (const float*)d_in[20]; a.bt2 = (const float*)d_in[21];
  a.Wt3 = (const float*)d_in[22]; a.bt3 = (const float*)d_in[23];
  a.out = (float*)d_out;
  a.wsw = (half_t*)d_ws;
  a.dts = (float*)((char*)d_ws + DTS_BYTE_OFF);

  swz_kernel<<<dim3(504), dim3(256), 0, stream>>>(a);
  dts_kernel<<<dim3(1), dim3(256), 0, stream>>>(a);
  odegru_kernel<<<dim3(16), dim3(1024), 0, stream>>>(a);
}